// Round 8
// baseline (396.137 us; speedup 1.0000x reference)
//
#include <hip/hip_runtime.h>
#include <hip/hip_bf16.h>
#include <cstdint>

#define NUM_TOKENS 8192
#define IN_DIM 4096
#define OUT_DIM 4096
#define NUM_AD 8
#define RANK 64
#define RTOT (NUM_AD * RANK)           // 512
#define KAUG (IN_DIM + RTOT)           // 4608

typedef __bf16 bf16x8 __attribute__((ext_vector_type(8)));
typedef float f32x4 __attribute__((ext_vector_type(4)));
typedef unsigned short ushort_t;

__device__ __forceinline__ unsigned f2bf_u(float f) {
  unsigned u = __float_as_uint(f);
  return (u + 0x7FFFu + ((u >> 16) & 1u)) >> 16;   // round-to-nearest-even
}
__device__ __forceinline__ uint2 pack4(float4 v) {
  uint2 r;
  r.x = f2bf_u(v.x) | (f2bf_u(v.y) << 16);
  r.y = f2bf_u(v.z) | (f2bf_u(v.w) << 16);
  return r;
}
__device__ __forceinline__ uint4 pack8(float4 a, float4 b) {
  uint2 p = pack4(a), q = pack4(b);
  return make_uint4(p.x, p.y, q.x, q.y);
}

#define AS1(p) (const __attribute__((address_space(1))) void*)(p)
#define AS3(p) (__attribute__((address_space(3))) void*)(p)
#define GLD(gp, lp) __builtin_amdgcn_global_load_lds(AS1(gp), AS3(lp), 16, 0, 0)

// ---------- Fused aux kernel: one launch does all pre-GEMM work ----------
// roles by blockIdx.x:
//   [0,512):        LoRA-A GEMM (reads x, A_buffer as f32; reg-staged cvt to LDS;
//                   bx==0 blocks also store converted x-tile -> Xaug cols 0..4095;
//                   epilogue writes masked Z -> Xaug cols 4096..4607)
//   [512, 8704):    wgt f32 -> Waug bf16 cols 0..4095   (8 elems/thread)
//   [8704, 9728):   B_buffer [8][4096][64] -> Waug cols 4096+a*64+r (8 elems/thread)
// Writes are disjoint; nothing written here is read within this kernel (each
// lora block consumes only its own LDS staging) -> race-free by construction.
#define LORA_BLKS 512
#define WGT_BLKS  8192
__global__ __launch_bounds__(256)
void k_fused_aux(const float* __restrict__ x, const float* __restrict__ wgt,
                 const float* __restrict__ Abuf, const float* __restrict__ Bbuf,
                 const int* __restrict__ aid,
                 ushort_t* __restrict__ Xaug, ushort_t* __restrict__ Waug) {
  __shared__ __align__(16) ushort_t As[128 * 32];   // 8 KB
  __shared__ __align__(16) ushort_t Bs[64 * 32];    // 4 KB
  const int bid = blockIdx.x;
  const int tid = threadIdx.x;

  if (bid >= LORA_BLKS) {
    if (bid < LORA_BLKS + WGT_BLKS) {   // wgt convert
      size_t idx = ((size_t)(bid - LORA_BLKS) * 256 + tid) << 3;
      int row = (int)(idx >> 12);
      int col = (int)(idx & 4095);
      float4 v0 = *reinterpret_cast<const float4*>(wgt + idx);
      float4 v1 = *reinterpret_cast<const float4*>(wgt + idx + 4);
      *reinterpret_cast<uint4*>(Waug + (size_t)row * KAUG + col) = pack8(v0, v1);
    } else {                             // B_buffer scatter
      size_t idx = ((size_t)(bid - LORA_BLKS - WGT_BLKS) * 256 + tid) << 3;
      int a = (int)(idx / (OUT_DIM * RANK));
      int rem = (int)(idx - (size_t)a * (OUT_DIM * RANK));
      int o = rem >> 6;
      int r = rem & 63;
      float4 v0 = *reinterpret_cast<const float4*>(Bbuf + idx);
      float4 v1 = *reinterpret_cast<const float4*>(Bbuf + idx + 4);
      *reinterpret_cast<uint4*>(Waug + (size_t)o * KAUG + IN_DIM + a * RANK + r) =
          pack8(v0, v1);
    }
    return;
  }

  // ---- LoRA-A role: C[8192,512] = x[8192,4096] @ Abuf[512,4096]^T, masked -> Z ----
  const int w = tid >> 6;
  const int l = tid & 63;
  const int wr = w >> 1, wc = w & 1;      // wave grid 2Mx2N; per-wave 64x32

  const int swz = (bid & 7) * 64 + (bid >> 3);   // XCD swizzle (512 = 8*64)
  const int by = swz >> 3, bx = swz & 7;
  const int brow = by << 7, bcol = bx << 6;

  // staging: thread t handles rows {sr, 64+sr} of A-tile and row sr of B-tile,
  // 8 consecutive K-elems at sc. LDS linear: byte 16*tid (conflict-free).
  const int sr = tid >> 2;            // 0..63
  const int sc = (tid & 3) << 3;      // 0,8,16,24
  const float* gx0 = x + (size_t)(brow + sr) * IN_DIM + sc;
  const float* gx1 = gx0 + (size_t)64 * IN_DIM;
  const float* gA  = Abuf + (size_t)(bcol + sr) * IN_DIM + sc;
  ushort_t* sa0 = As + sr * 32 + sc;
  ushort_t* sa1 = As + (64 + sr) * 32 + sc;
  ushort_t* sbp = Bs + sr * 32 + sc;
  ushort_t* xo0 = Xaug + (size_t)(brow + sr) * KAUG + sc;
  ushort_t* xo1 = xo0 + (size_t)64 * KAUG;
  const bool wx = (bx == 0);          // this block writes Xaug cols 0..4095

  const int lr = l & 15;
  const int lkb = (l >> 4) << 3;
  const ushort_t* fa = As + (wr * 64 + lr) * 32 + lkb;
  const ushort_t* fb = Bs + (wc * 32 + lr) * 32 + lkb;

  f32x4 acc[4][2] = {};

  for (int k0 = 0; k0 < IN_DIM; k0 += 32) {
    float4 a00 = *reinterpret_cast<const float4*>(gx0 + k0);
    float4 a01 = *reinterpret_cast<const float4*>(gx0 + k0 + 4);
    float4 a10 = *reinterpret_cast<const float4*>(gx1 + k0);
    float4 a11 = *reinterpret_cast<const float4*>(gx1 + k0 + 4);
    float4 b0  = *reinterpret_cast<const float4*>(gA + k0);
    float4 b1  = *reinterpret_cast<const float4*>(gA + k0 + 4);
    uint4 va0 = pack8(a00, a01);
    uint4 va1 = pack8(a10, a11);
    uint4 vb  = pack8(b0, b1);
    *reinterpret_cast<uint4*>(sa0) = va0;
    *reinterpret_cast<uint4*>(sa1) = va1;
    *reinterpret_cast<uint4*>(sbp) = vb;
    if (wx) {
      *reinterpret_cast<uint4*>(xo0 + k0) = va0;
      *reinterpret_cast<uint4*>(xo1 + k0) = va1;
    }
    __syncthreads();
    bf16x8 av[4], bv[2];
#pragma unroll
    for (int mb = 0; mb < 4; ++mb)
      av[mb] = *reinterpret_cast<const bf16x8*>(fa + mb * 16 * 32);
#pragma unroll
    for (int nb = 0; nb < 2; ++nb)
      bv[nb] = *reinterpret_cast<const bf16x8*>(fb + nb * 16 * 32);
#pragma unroll
    for (int mb = 0; mb < 4; ++mb)
#pragma unroll
      for (int nb = 0; nb < 2; ++nb)
        acc[mb][nb] = __builtin_amdgcn_mfma_f32_16x16x32_bf16(av[mb], bv[nb], acc[mb][nb], 0, 0, 0);
    __syncthreads();
  }

  const int orow = brow + wr * 64 + ((l >> 4) << 2);
#pragma unroll
  for (int mb = 0; mb < 4; ++mb) {
#pragma unroll
    for (int j = 0; j < 4; ++j) {
      int t = orow + mb * 16 + j;
      int ad = aid[t];
#pragma unroll
      for (int nb = 0; nb < 2; ++nb) {
        int cc = bcol + wc * 32 + nb * 16 + lr;
        float v = ((cc >> 6) == ad) ? acc[mb][nb][j] : 0.f;
        Xaug[(size_t)t * KAUG + IN_DIM + cc] = (ushort_t)f2bf_u(v);
      }
    }
  }
}

// ---------- 256^2-tile sparse-barrier counted-vmcnt GEMM (R5-exact, best: 244 µs) ----------
// C[M,N] = A[M,K](lda) x B[N,K](ldb)^T + bias.  M,N % 256 == 0, K % 128 == 0.
// 8 waves (2Mx4N), per-wave C = 128x64. LDS 128KB: 2 bufs x (A:2x16KB | B:2x16KB).
// 2 barriers + 2 vmcnt(4) per K-tile. B-frags register-pipelined (late LDBH).
// T2 read-swizzle: byte ^= ((row&7)<<4); source pre-swizzled (same involution).
// Schedule lessons: R6 single-barrier (-6 µs) and R7 quadrant-pipeline (-11 µs)
// both LOST to this; R4's 32x32x16 fragments tripped 2.8e7 bank conflicts.
__global__ __launch_bounds__(512, 2)
void gemm8(const ushort_t* __restrict__ A, int lda,
           const ushort_t* __restrict__ B, int ldb,
           int M, int N, int K,
           float* __restrict__ out, const float* __restrict__ bias) {
  extern __shared__ char lds[];
  const int tid = threadIdx.x;
  const int l = tid & 63;
  const int w = tid >> 6;       // 0..7
  const int wr = w >> 2;        // 0..1  (A-half / M-half ownership)
  const int wc = w & 3;         // 0..3  (N ownership: B-half wc>>1, 64-col slice wc&1)

  const int nbx = N >> 8;
  const int nwg = nbx * (M >> 8);
  const int cpx = nwg >> 3;     // nwg % 8 == 0 for all our launches
  const int bid = blockIdx.x;
  const int swz = (bid & 7) * cpx + (bid >> 3);
  const int by = swz / nbx, bx = swz - by * nbx;
  const int brow = by << 8, bcol = bx << 8;

  const int r0 = tid >> 3;                        // 0..63
  const int kc = ((tid & 7) ^ (r0 & 7)) << 3;     // element col, same involution as read

  const int lr = l & 15;
  const int lxor = (l & 7) << 4;                  // (row&7)<<4
  const int kb0 = (l >> 4) << 4;                  // 0,16,32,48 bytes

  const int NT = K >> 6;         // K-tiles (even)
  const int NIT = NT >> 1;

#define STG(mat, ld, rowbase, kt_, half, isB) do {                                   \
    int kt = (kt_); if (kt >= NT) kt -= NT;                                          \
    char* lb = lds + (((kt & 1) << 16) | ((isB) << 15) | ((half) << 14) | (w << 10));\
    const ushort_t* sp = (mat) + (size_t)((rowbase) + ((half) << 7) + r0) * (ld)     \
                         + (kt << 6) + kc;                                           \
    GLD(sp, lb);                                                                     \
    GLD(sp + 64 * (ld), lb + 8192);                                                  \
  } while (0)

#define LDA_ADDR(c, q, m, ks)                                                        \
  (const bf16x8*)(lds + (((c) << 16) | (wr << 14))                                   \
                  + ((q) * 32 + (m) * 16 + lr) * 128 + ((((ks) << 6) | kb0) ^ lxor))
#define LDB_ADDR(c, n, ks)                                                           \
  (const bf16x8*)(lds + (((c) << 16) | 32768 | ((wc >> 1) << 14))                    \
                  + (((wc & 1) << 6) + (n) * 16 + lr) * 128 + ((((ks) << 6) | kb0) ^ lxor))

  f32x4 acc[8][4] = {};
  bf16x8 bfr[4][2];   // B-frags for the CURRENT tile; reloaded (next tile) at
                      // the end of each tile's second region (WAR-ordered).

#define LDBH(c, h, dst) do {                                                         \
    _Pragma("unroll") for (int n = 2 * (h); n < 2 * (h) + 2; ++n)                    \
      _Pragma("unroll") for (int ks = 0; ks < 2; ++ks)                               \
        dst[n][ks] = *LDB_ADDR(c, n, ks);                                            \
  } while (0)

#define MFMAQ(q, a_, bfr_)                                                           \
    _Pragma("unroll") for (int ks = 0; ks < 2; ++ks)                                 \
      _Pragma("unroll") for (int m = 0; m < 2; ++m)                                  \
        _Pragma("unroll") for (int n = 0; n < 4; ++n)                                \
          acc[2 * (q) + m][n] = __builtin_amdgcn_mfma_f32_16x16x32_bf16(             \
              a_[m][ks], bfr_[n][ks], acc[2 * (q) + m][n], 0, 0, 0)

  // prologue: T0 A+B complete, T1.B in flight; B(0)->bfr in registers
  STG(A, lda, brow, 0, 0, 0);
  STG(A, lda, brow, 0, 1, 0);
  STG(B, ldb, bcol, 0, 0, 1);
  STG(B, ldb, bcol, 0, 1, 1);
  STG(B, ldb, bcol, 1, 0, 1);
  STG(B, ldb, bcol, 1, 1, 1);
  asm volatile("s_waitcnt vmcnt(4)" ::: "memory");
  __builtin_amdgcn_s_barrier();
  __builtin_amdgcn_sched_barrier(0);
  LDBH(0, 0, bfr);
  LDBH(0, 1, bfr);

  // one K-tile: region01 {A-reads q0,q1 | stage A(T+1) | MFMA q0,q1 | vmcnt(4) bar}
  //             region23 {A-reads q2,q3 | stage B(T+2) | MFMA q2,q3 |
  //                       late-load bfr <- B(T+1) | vmcnt(4) bar}
#define TILE(c, TA, TB) do {                                                         \
    {                                                                                \
      bf16x8 a0[2][2], a1[2][2];                                                     \
      _Pragma("unroll") for (int m = 0; m < 2; ++m)                                  \
        _Pragma("unroll") for (int ks = 0; ks < 2; ++ks) {                           \
          a0[m][ks] = *LDA_ADDR(c, 0, m, ks);                                        \
          a1[m][ks] = *LDA_ADDR(c, 1, m, ks);                                        \
        }                                                                            \
      STG(A, lda, brow, TA, 0, 0);                                                   \
      STG(A, lda, brow, TA, 1, 0);                                                   \
      __builtin_amdgcn_s_setprio(1);                                                 \
      MFMAQ(0, a0, bfr);                                                             \
      MFMAQ(1, a1, bfr);                                                             \
      __builtin_amdgcn_s_setprio(0);                                                 \
      asm volatile("s_waitcnt vmcnt(4)" ::: "memory");                               \
      __builtin_amdgcn_s_barrier();                                                  \
      __builtin_amdgcn_sched_barrier(0);                                             \
    }                                                                                \
    {                                                                                \
      bf16x8 a0[2][2], a1[2][2];                                                     \
      _Pragma("unroll") for (int m = 0; m < 2; ++m)                                  \
        _Pragma("unroll") for (int ks = 0; ks < 2; ++ks) {                           \
          a0[m][ks] = *LDA_ADDR(c, 2, m, ks);                                        \
          a1[m][ks] = *LDA_ADDR(c, 3, m, ks);                                        \
        }                                                                            \
      STG(B, ldb, bcol, TB, 0, 1);                                                   \
      STG(B, ldb, bcol, TB, 1, 1);                                                   \
      __builtin_amdgcn_s_setprio(1);                                                 \
      MFMAQ(2, a0, bfr);                                                             \
      MFMAQ(3, a1, bfr);                                                             \
      __builtin_amdgcn_s_setprio(0);                                                 \
      LDBH((c) ^ 1, 0, bfr);                                                         \
      LDBH((c) ^ 1, 1, bfr);                                                         \
      asm volatile("s_waitcnt vmcnt(4)" ::: "memory");                               \
      __builtin_amdgcn_s_barrier();                                                  \
      __builtin_amdgcn_sched_barrier(0);                                             \
    }                                                                                \
  } while (0)

  for (int it = 0; it < NIT; ++it) {
    const int T = it << 1;
    TILE(0, T + 1, T + 2);
    TILE(1, T + 2, T + 3);
  }

  // epilogue: D frag layout row=(l>>4)*4+j, col=l&15 (verified R1-R7)
  const int orow = brow + (wr << 7) + ((l >> 4) << 2);
  const int ocol = bcol + (wc << 6) + lr;
  float bb[4];
#pragma unroll
  for (int n = 0; n < 4; ++n) bb[n] = bias[ocol + n * 16];
#pragma unroll
  for (int mi = 0; mi < 8; ++mi)
#pragma unroll
    for (int n = 0; n < 4; ++n)
#pragma unroll
      for (int j = 0; j < 4; ++j)
        out[(size_t)(orow + mi * 16 + j) * N + ocol + n * 16] = acc[mi][n][j] + bb[n];
}

extern "C" void kernel_launch(void* const* d_in, const int* in_sizes, int n_in,
                              void* d_out, int out_size, void* d_ws, size_t ws_size,
                              hipStream_t stream) {
  const float* x    = (const float*)d_in[0];
  const float* wgt  = (const float*)d_in[1];
  const float* bias = (const float*)d_in[2];
  const float* Abuf = (const float*)d_in[3];
  const float* Bbuf = (const float*)d_in[4];
  const int*   aid  = (const int*)d_in[5];
  float* out = (float*)d_out;

  // workspace: Xaug[8192][4608] | Waug[4096][4608]   (bf16 as ushort)
  ushort_t* Xaug = (ushort_t*)d_ws;
  ushort_t* Waug = Xaug + (size_t)NUM_TOKENS * KAUG;

  // fused aux: LoRA-A GEMM (+Xaug x-conversion) + wgt/B conversions, one launch
  k_fused_aux<<<LORA_BLKS + WGT_BLKS + 1024, 256, 0, stream>>>(
      x, wgt, Abuf, Bbuf, aid, Xaug, Waug);

  // out = Xaug @ Waug^T + bias: M=8192 N=4096 K=4608 (72 K-tiles, 36 iters)
  gemm8<<<(NUM_TOKENS / 256) * (OUT_DIM / 256), 512, 131072, stream>>>(
      Xaug, KAUG, Waug, KAUG, NUM_TOKENS, OUT_DIM, KAUG, out, bias);
}

// Round 10
// 325.860 us; speedup vs baseline: 1.2157x; 1.2157x over previous
//
#include <hip/hip_runtime.h>
#include <hip/hip_bf16.h>
#include <cstdint>

#define NUM_TOKENS 8192
#define IN_DIM 4096
#define OUT_DIM 4096
#define NUM_AD 8
#define RANK 64
#define RTOT (NUM_AD * RANK)           // 512
#define KAUG (IN_DIM + RTOT)           // 4608

typedef __bf16 bf16x8 __attribute__((ext_vector_type(8)));
typedef float f32x4 __attribute__((ext_vector_type(4)));
typedef unsigned short ushort_t;

__device__ __forceinline__ unsigned f2bf_u(float f) {
  unsigned u = __float_as_uint(f);
  return (u + 0x7FFFu + ((u >> 16) & 1u)) >> 16;   // round-to-nearest-even
}
__device__ __forceinline__ uint2 pack4(float4 v) {
  uint2 r;
  r.x = f2bf_u(v.x) | (f2bf_u(v.y) << 16);
  r.y = f2bf_u(v.z) | (f2bf_u(v.w) << 16);
  return r;
}
__device__ __forceinline__ uint4 pack8(float4 a, float4 b) {
  uint2 p = pack4(a), q = pack4(b);
  return make_uint4(p.x, p.y, q.x, q.y);
}

#define AS1(p) (const __attribute__((address_space(1))) void*)(p)
#define AS3(p) (__attribute__((address_space(3))) void*)(p)
#define GLD(gp, lp) __builtin_amdgcn_global_load_lds(AS1(gp), AS3(lp), 16, 0, 0)
#define LGKM(n) asm volatile("s_waitcnt lgkmcnt(" #n ")" ::: "memory")
#define VMC(n)  asm volatile("s_waitcnt vmcnt(" #n ")" ::: "memory")
#define SB()    __builtin_amdgcn_sched_barrier(0)

// ---------- One merged conversion kernel: x, wgt, A_buffer, B_buffer -> bf16 ----------
// 8 elems/thread, range-branched. Pure streaming, no inter-range interaction.
#define XT8 (NUM_TOKENS * IN_DIM / 8)         // 4194304
#define WT8 (OUT_DIM * IN_DIM / 8)            // 2097152
#define AT8 (RTOT * IN_DIM / 8)               //  262144
#define BT8 (NUM_AD * OUT_DIM * RANK / 8)     //  262144
__global__ void k_cvt_all(const float* __restrict__ x, const float* __restrict__ wgt,
                          const float* __restrict__ Abuf, const float* __restrict__ Bbuf,
                          ushort_t* __restrict__ Xaug, ushort_t* __restrict__ Waug,
                          ushort_t* __restrict__ Abf) {
  int i = blockIdx.x * blockDim.x + threadIdx.x;
  if (i < XT8 + WT8) {                 // x -> Xaug cols 0..4095 | wgt -> Waug cols 0..4095
    const float* src = (i < XT8) ? x : wgt;
    ushort_t* dst = (i < XT8) ? Xaug : Waug;
    size_t idx = ((size_t)(i < XT8 ? i : i - XT8)) << 3;
    int row = (int)(idx >> 12);
    int col = (int)(idx & 4095);
    float4 v0 = *reinterpret_cast<const float4*>(src + idx);
    float4 v1 = *reinterpret_cast<const float4*>(src + idx + 4);
    *reinterpret_cast<uint4*>(dst + (size_t)row * KAUG + col) = pack8(v0, v1);
  } else if (i < XT8 + WT8 + AT8) {    // A_buffer -> Abf flat [512][4096]
    size_t idx = ((size_t)(i - XT8 - WT8)) << 3;
    float4 v0 = *reinterpret_cast<const float4*>(Abuf + idx);
    float4 v1 = *reinterpret_cast<const float4*>(Abuf + idx + 4);
    *reinterpret_cast<uint4*>(Abf + idx) = pack8(v0, v1);
  } else {                             // B_buffer [8][4096][64] -> Waug cols 4096+a*64+r
    size_t idx = ((size_t)(i - XT8 - WT8 - AT8)) << 3;
    int a = (int)(idx >> 18);
    int rem = (int)(idx & 262143);
    int o = rem >> 6;
    int r = rem & 63;
    float4 v0 = *reinterpret_cast<const float4*>(Bbuf + idx);
    float4 v1 = *reinterpret_cast<const float4*>(Bbuf + idx + 4);
    *reinterpret_cast<uint4*>(Waug + (size_t)o * KAUG + IN_DIM + a * RANK + r) = pack8(v0, v1);
  }
}

// ---------- LoRA-A GEMM v2: 128x64 tile, 4 waves, BK=64, dbuf + counted vmcnt ----------
// C[8192,512] = Xaug[:, 0:4096 (ld KAUG)] @ Abf[512,4096]^T; masked bf16 -> Z cols.
// LDS 48KB dyn: A bufs @ c*16384 (16KB, 128 rows x 128B), B bufs @ 32768 + c*8192.
// R9 bug + fix: global_load_lds dest is WAVE-uniform base + lane*16 (m104) — the
// per-wave (w<<10) offset was missing, so all 4 waves wrote the same 1KB slice.
// Now: thread t=64w+l writes LDS byte chunk + t*16 -> row t>>3 = source row r0,
// byte-in-row (t&7)*16 = pre-swizzled source col kc (write/read same involution).
// Ledger: 2 raw barriers + vmcnt(6)/tile. Post-VMC barrier makes OTHER waves'
// staged slices visible (staging is distributed across waves).
__global__ __launch_bounds__(256)
void gemm_lora_a(const ushort_t* __restrict__ A, const ushort_t* __restrict__ B,
                 ushort_t* __restrict__ Z, const int* __restrict__ aid) {
  extern __shared__ char lds[];
  const int tid = threadIdx.x;
  const int w = tid >> 6;
  const int l = tid & 63;
  const int wr = w >> 1, wc = w & 1;      // wave grid 2Mx2N; per-wave 64x32

  const int bid = blockIdx.x;             // nwg = 512 = 8*64 (XCD swizzle exact)
  const int swz = (bid & 7) * 64 + (bid >> 3);
  const int by = swz >> 3, bx = swz & 7;
  const int brow = by << 7, bcol = bx << 6;

  const int r0 = tid >> 3;                        // 0..31 (row within 32-row gld chunk)
  const int kc = ((tid & 7) ^ (r0 & 7)) << 3;     // pre-swizzled source col (elems)
  const int wofs = w << 10;                       // per-wave LDS slice (THE R9 FIX)

  const int lr = l & 15;
  const int lxor = (l & 7) << 4;
  const int kb0 = (l >> 4) << 4;

  // stage tile kt (64 cols): A 4 glds (32 rows each), B 2 glds
#define STGL(k_) do {                                                                \
    int kt = (k_); if (kt >= 64) kt -= 64;                                           \
    char* ab = lds + ((kt & 1) << 14) + wofs;                                        \
    char* bb = lds + 32768 + ((kt & 1) << 13) + wofs;                                \
    const ushort_t* spa = A + (size_t)(brow + r0) * KAUG + (kt << 6) + kc;           \
    const ushort_t* spb = B + (size_t)(bcol + r0) * IN_DIM + (kt << 6) + kc;         \
    GLD(spa, ab);                                                                    \
    GLD(spa + (size_t)32 * KAUG, ab + 4096);                                         \
    GLD(spa + (size_t)64 * KAUG, ab + 8192);                                         \
    GLD(spa + (size_t)96 * KAUG, ab + 12288);                                        \
    GLD(spb, bb);                                                                    \
    GLD(spb + (size_t)32 * IN_DIM, bb + 4096);                                       \
  } while (0)

#define LAADDR(c, mb, ks)                                                            \
  (const bf16x8*)(lds + ((c) << 14)                                                  \
                  + (wr * 64 + (mb) * 16 + lr) * 128 + ((((ks) << 6) | kb0) ^ lxor))
#define LBADDR(c, nb, ks)                                                            \
  (const bf16x8*)(lds + 32768 + ((c) << 13)                                          \
                  + (wc * 32 + (nb) * 16 + lr) * 128 + ((((ks) << 6) | kb0) ^ lxor))

  f32x4 acc[4][2] = {};

  STGL(0);
  STGL(1);
  VMC(6);
  __builtin_amdgcn_s_barrier();
  SB();

  for (int k = 0; k < 64; ++k) {
    const int c = k & 1;
    bf16x8 af[4][2], bf[2][2];
#pragma unroll
    for (int mb = 0; mb < 4; ++mb)
#pragma unroll
      for (int ks = 0; ks < 2; ++ks)
        af[mb][ks] = *LAADDR(c, mb, ks);
#pragma unroll
    for (int nb = 0; nb < 2; ++nb)
#pragma unroll
      for (int ks = 0; ks < 2; ++ks)
        bf[nb][ks] = *LBADDR(c, nb, ks);
    LGKM(0); SB();
    __builtin_amdgcn_s_barrier();      // all waves' reads of buf c drained
    STGL(k + 2);                       // overwrite buf c with tile k+2
    __builtin_amdgcn_s_setprio(1);
#pragma unroll
    for (int ks = 0; ks < 2; ++ks)
#pragma unroll
      for (int mb = 0; mb < 4; ++mb)
#pragma unroll
        for (int nb = 0; nb < 2; ++nb)
          acc[mb][nb] = __builtin_amdgcn_mfma_f32_16x16x32_bf16(
              af[mb][ks], bf[nb][ks], acc[mb][nb], 0, 0, 0);
    __builtin_amdgcn_s_setprio(0);
    VMC(6);                            // own slices of tile k+1 landed
    __builtin_amdgcn_s_barrier();      // everyone's slices of k+1 visible
    SB();
  }

  const int orow = brow + wr * 64 + ((l >> 4) << 2);
#pragma unroll
  for (int mb = 0; mb < 4; ++mb) {
#pragma unroll
    for (int j = 0; j < 4; ++j) {
      int t = orow + mb * 16 + j;
      int ad = aid[t];
#pragma unroll
      for (int nb = 0; nb < 2; ++nb) {
        int cc = bcol + wc * 32 + nb * 16 + lr;
        float v = ((cc >> 6) == ad) ? acc[mb][nb][j] : 0.f;
        Z[(size_t)t * KAUG + IN_DIM + cc] = (ushort_t)f2bf_u(v);
      }
    }
  }
}

// ---------- 256^2-tile sparse-barrier counted-vmcnt GEMM (R5-exact, best: 244 µs) ----------
// C[M,N] = A[M,K](lda) x B[N,K](ldb)^T + bias.  M,N % 256 == 0, K % 128 == 0.
// 8 waves (2Mx4N), per-wave C = 128x64. LDS 128KB: 2 bufs x (A:2x16KB | B:2x16KB).
// 2 barriers + 2 vmcnt(4) per K-tile. B-frags register-pipelined (late LDBH).
// T2 read-swizzle: byte ^= ((row&7)<<4); source pre-swizzled (same involution).
// Closed schedule search: R6 single-barrier and R7 quadrant-pipeline both lost;
// R4's 32x32x16 fragments tripped 2.8e7 bank conflicts. This is the keeper.
__global__ __launch_bounds__(512, 2)
void gemm8(const ushort_t* __restrict__ A, int lda,
           const ushort_t* __restrict__ B, int ldb,
           int M, int N, int K,
           float* __restrict__ out, const float* __restrict__ bias) {
  extern __shared__ char lds[];
  const int tid = threadIdx.x;
  const int l = tid & 63;
  const int w = tid >> 6;       // 0..7
  const int wr = w >> 2;        // 0..1  (A-half / M-half ownership)
  const int wc = w & 3;         // 0..3  (N ownership: B-half wc>>1, 64-col slice wc&1)

  const int nbx = N >> 8;
  const int nwg = nbx * (M >> 8);
  const int cpx = nwg >> 3;     // nwg % 8 == 0 for all our launches
  const int bid = blockIdx.x;
  const int swz = (bid & 7) * cpx + (bid >> 3);
  const int by = swz / nbx, bx = swz - by * nbx;
  const int brow = by << 8, bcol = bx << 8;

  const int r0 = tid >> 3;                        // 0..63
  const int kc = ((tid & 7) ^ (r0 & 7)) << 3;     // element col, same involution as read

  const int lr = l & 15;
  const int lxor = (l & 7) << 4;                  // (row&7)<<4
  const int kb0 = (l >> 4) << 4;                  // 0,16,32,48 bytes

  const int NT = K >> 6;         // K-tiles (even)
  const int NIT = NT >> 1;

#define STG(mat, ld, rowbase, kt_, half, isB) do {                                   \
    int kt = (kt_); if (kt >= NT) kt -= NT;                                          \
    char* lb = lds + (((kt & 1) << 16) | ((isB) << 15) | ((half) << 14) | (w << 10));\
    const ushort_t* sp = (mat) + (size_t)((rowbase) + ((half) << 7) + r0) * (ld)     \
                         + (kt << 6) + kc;                                           \
    GLD(sp, lb);                                                                     \
    GLD(sp + 64 * (ld), lb + 8192);                                                  \
  } while (0)

#define LDA_ADDR(c, q, m, ks)                                                        \
  (const bf16x8*)(lds + (((c) << 16) | (wr << 14))                                   \
                  + ((q) * 32 + (m) * 16 + lr) * 128 + ((((ks) << 6) | kb0) ^ lxor))
#define LDB_ADDR(c, n, ks)                                                           \
  (const bf16x8*)(lds + (((c) << 16) | 32768 | ((wc >> 1) << 14))                    \
                  + (((wc & 1) << 6) + (n) * 16 + lr) * 128 + ((((ks) << 6) | kb0) ^ lxor))

  f32x4 acc[8][4] = {};
  bf16x8 bfr[4][2];   // B-frags for the CURRENT tile; reloaded (next tile) at
                      // the end of each tile's second region (WAR-ordered).

#define LDBH(c, h, dst) do {                                                         \
    _Pragma("unroll") for (int n = 2 * (h); n < 2 * (h) + 2; ++n)                    \
      _Pragma("unroll") for (int ks = 0; ks < 2; ++ks)                               \
        dst[n][ks] = *LDB_ADDR(c, n, ks);                                            \
  } while (0)

#define MFMAQ(q, a_, bfr_)                                                           \
    _Pragma("unroll") for (int ks = 0; ks < 2; ++ks)                                 \
      _Pragma("unroll") for (int m = 0; m < 2; ++m)                                  \
        _Pragma("unroll") for (int n = 0; n < 4; ++n)                                \
          acc[2 * (q) + m][n] = __builtin_amdgcn_mfma_f32_16x16x32_bf16(             \
              a_[m][ks], bfr_[n][ks], acc[2 * (q) + m][n], 0, 0, 0)

  // prologue: T0 A+B complete, T1.B in flight; B(0)->bfr in registers
  STG(A, lda, brow, 0, 0, 0);
  STG(A, lda, brow, 0, 1, 0);
  STG(B, ldb, bcol, 0, 0, 1);
  STG(B, ldb, bcol, 0, 1, 1);
  STG(B, ldb, bcol, 1, 0, 1);
  STG(B, ldb, bcol, 1, 1, 1);
  VMC(4);
  __builtin_amdgcn_s_barrier();
  SB();
  LDBH(0, 0, bfr);
  LDBH(0, 1, bfr);

  // one K-tile: region01 {A-reads q0,q1 | stage A(T+1) | MFMA q0,q1 | vmcnt(4) bar}
  //             region23 {A-reads q2,q3 | stage B(T+2) | MFMA q2,q3 |
  //                       late-load bfr <- B(T+1) | vmcnt(4) bar}
#define TILE(c, TA, TB) do {                                                         \
    {                                                                                \
      bf16x8 a0[2][2], a1[2][2];                                                     \
      _Pragma("unroll") for (int m = 0; m < 2; ++m)                                  \
        _Pragma("unroll") for (int ks = 0; ks < 2; ++ks) {                           \
          a0[m][ks] = *LDA_ADDR(c, 0, m, ks);                                        \
          a1[m][ks] = *LDA_ADDR(c, 1, m, ks);                                        \
        }                                                                            \
      STG(A, lda, brow, TA, 0, 0);                                                   \
      STG(A, lda, brow, TA, 1, 0);                                                   \
      __builtin_amdgcn_s_setprio(1);                                                 \
      MFMAQ(0, a0, bfr);                                                             \
      MFMAQ(1, a1, bfr);                                                             \
      __builtin_amdgcn_s_setprio(0);                                                 \
      VMC(4);                                                                        \
      __builtin_amdgcn_s_barrier();                                                  \
      SB();                                                                          \
    }                                                                                \
    {                                                                                \
      bf16x8 a0[2][2], a1[2][2];                                                     \
      _Pragma("unroll") for (int m = 0; m < 2; ++m)                                  \
        _Pragma("unroll") for (int ks = 0; ks < 2; ++ks) {                           \
          a0[m][ks] = *LDA_ADDR(c, 2, m, ks);                                        \
          a1[m][ks] = *LDA_ADDR(c, 3, m, ks);                                        \
        }                                                                            \
      STG(B, ldb, bcol, TB, 0, 1);                                                   \
      STG(B, ldb, bcol, TB, 1, 1);                                                   \
      __builtin_amdgcn_s_setprio(1);                                                 \
      MFMAQ(2, a0, bfr);                                                             \
      MFMAQ(3, a1, bfr);                                                             \
      __builtin_amdgcn_s_setprio(0);                                                 \
      LDBH((c) ^ 1, 0, bfr);                                                         \
      LDBH((c) ^ 1, 1, bfr);                                                         \
      VMC(4);                                                                        \
      __builtin_amdgcn_s_barrier();                                                  \
      SB();                                                                          \
    }                                                                                \
  } while (0)

  for (int it = 0; it < NIT; ++it) {
    const int T = it << 1;
    TILE(0, T + 1, T + 2);
    TILE(1, T + 2, T + 3);
  }

  // epilogue: D frag layout row=(l>>4)*4+j, col=l&15 (verified R1-R8)
  const int orow = brow + (wr << 7) + ((l >> 4) << 2);
  const int ocol = bcol + (wc << 6) + lr;
  float bb[4];
#pragma unroll
  for (int n = 0; n < 4; ++n) bb[n] = bias[ocol + n * 16];
#pragma unroll
  for (int mi = 0; mi < 8; ++mi)
#pragma unroll
    for (int n = 0; n < 4; ++n)
#pragma unroll
      for (int j = 0; j < 4; ++j)
        out[(size_t)(orow + mi * 16 + j) * N + ocol + n * 16] = acc[mi][n][j] + bb[n];
}

extern "C" void kernel_launch(void* const* d_in, const int* in_sizes, int n_in,
                              void* d_out, int out_size, void* d_ws, size_t ws_size,
                              hipStream_t stream) {
  const float* x    = (const float*)d_in[0];
  const float* wgt  = (const float*)d_in[1];
  const float* bias = (const float*)d_in[2];
  const float* Abuf = (const float*)d_in[3];
  const float* Bbuf = (const float*)d_in[4];
  const int*   aid  = (const int*)d_in[5];
  float* out = (float*)d_out;

  // workspace: Xaug[8192][4608] | Waug[4096][4608] | Abf[512][4096]  (bf16 as ushort)
  ushort_t* Xaug = (ushort_t*)d_ws;
  ushort_t* Waug = Xaug + (size_t)NUM_TOKENS * KAUG;
  ushort_t* Abf  = Waug + (size_t)OUT_DIM * KAUG;

  // all conversions in one streaming launch
  k_cvt_all<<<(XT8 + WT8 + AT8 + BT8) / 256, 256, 0, stream>>>(
      x, wgt, Abuf, Bbuf, Xaug, Waug, Abf);

  // Z = mask(X @ A_flat^T) into Xaug cols 4096..4607: M=8192 N=512 K=4096
  gemm_lora_a<<<512, 256, 49152, stream>>>(Xaug, Abf, Xaug, aid);

  // out = Xaug @ Waug^T + bias: M=8192 N=4096 K=4608 (72 K-tiles, 36 iters)
  gemm8<<<(NUM_TOKENS / 256) * (OUT_DIM / 256), 512, 131072, stream>>>(
      Xaug, KAUG, Waug, KAUG, NUM_TOKENS, OUT_DIM, KAUG, out, bias);
}